// Round 6
// baseline (575.875 us; speedup 1.0000x reference)
//
#include <hip/hip_runtime.h>
#include <math.h>

#define BB 128
#define TT 160
#define CC 6000
#define UU 32
#define BLANK (CC - 1)
#define NEGV (-1e30f)
#define EPSV (1e-7f)
#define NTHR 1024       // 16 waves: gather TLP; wave 0 runs the DP

// fast 3-way logsumexp: max3 -> one exp/log round-trip.
// Max term contributes exp(0)=1 exactly, so s>=1 and __logf's absolute
// error ~1e-7 — negligible vs loss magnitudes. (Measured: passes, absmax 0.)
__device__ __forceinline__ float lse3(float a, float b, float c) {
    float m = fmaxf(fmaxf(a, b), c);          // -> v_max3_f32
    float s = __expf(a - m) + __expf(b - m) + __expf(c - m);
    return m + __logf(s);
}
__device__ __forceinline__ float lse2(float a, float b) {
    float m = fmaxf(a, b);
    float s = __expf(a - m) + __expf(b - m);
    return m + __logf(s);
}

__global__ __launch_bounds__(NTHR) void ctc_fused_kernel(
    const int*   __restrict__ y_true,        // [B,U]
    const float* __restrict__ y_pred,        // [B,T,C] probabilities
    const int*   __restrict__ input_length,  // [B,1]
    const int*   __restrict__ label_length,  // [B,1]
    float*       __restrict__ out)           // [B,1]
{
    __shared__ float lpb[TT];        // log p(blank) per frame        (640 B)
    __shared__ float lpl[TT * UU];   // log p(label u) per frame   (20,480 B)
    __shared__ int   yt[UU];

    const int b   = blockIdx.x;
    const int tid = threadIdx.x;

    if (tid < UU) yt[tid] = y_true[b * UU + tid];
    __syncthreads();

    const int len = input_length[b];   // 120..160
    const int L   = label_length[b];   // 8..32

    // ---- gather phase: 16 waves, ~5 loads/thread, rows t < len only ----
    const float* yp = y_pred + (size_t)b * TT * CC;
    for (int t = tid; t < len; t += NTHR)
        lpb[t] = logf(yp[t * CC + BLANK] + EPSV);
    const int nl = len * UU;
    for (int i = tid; i < nl; i += NTHR) {
        int t = i >> 5;
        int u = i & 31;
        lpl[i] = logf(yp[t * CC + yt[u]] + EPSV);
    }
    __syncthreads();

    // ---- serial DP on wave 0 only; other 15 waves exit ----
    if (tid >= 64) return;
    const int  lane = tid;
    const bool odd  = lane & 1;
    const int  u    = lane >> 1;

    // skip transition s-2 -> s: s odd, s>=3, label[u] != label[u-1]
    const bool skip = odd && (lane >= 3) && (yt[u] != yt[u - 1]);

    // alpha(t=0): s=0 (blank) and s=1 (first label) live
    float a   = (lane == 0) ? lpb[0] : (lane == 1) ? lpl[0] : NEGV;
    float a64 = NEGV;                 // state s=64 (final blank), scalar

    // distance-2 register prefetch (len >= 120 guarantees rows 1,2 exist)
    float c0B = lpb[1], c0 = odd ? lpl[1 * UU + u] : c0B;   // row t=1
    float c1B = lpb[2], c1 = odd ? lpl[2 * UU + u] : c1B;   // row t=2

    for (int t = 1; t < len; ++t) {
        int tp = t + 2; if (tp >= len) tp = len - 1;
        float nB = lpb[tp];
        float nl_ = odd ? lpl[tp * UU + u] : nB;

        float a63 = __shfl(a, 63);
        float p1  = __shfl_up(a, 1);
        float p2  = __shfl_up(a, 2);
        if (lane < 1) p1 = NEGV;
        if (lane < 2) p2 = NEGV;

        float nv  = lse3(a, p1, skip ? p2 : NEGV) + c0;
        float n64 = lse2(a64, a63) + c0B;         // s=64: final blank, no skip

        a   = nv;
        a64 = n64;
        c0 = c1;  c0B = c1B;
        c1 = nl_; c1B = nB;
    }

    // loss = -logaddexp(alpha[2L], alpha[2L-1]),  2L in [16,64]
    const int e = 2 * L;
    float ae  = (e == 64) ? a64 : __shfl(a, e);
    float ae1 = __shfl(a, e - 1);                 // e-1 <= 63 always

    if (lane == 0) out[b] = -lse2(ae, ae1);
}

extern "C" void kernel_launch(void* const* d_in, const int* in_sizes, int n_in,
                              void* d_out, int out_size, void* d_ws, size_t ws_size,
                              hipStream_t stream) {
    const int*   y_true       = (const int*)  d_in[0];
    const float* y_pred       = (const float*)d_in[1];
    const int*   input_length = (const int*)  d_in[2];
    const int*   label_length = (const int*)  d_in[3];
    float*       out          = (float*)      d_out;

    ctc_fused_kernel<<<BB, NTHR, 0, stream>>>(y_true, y_pred, input_length,
                                              label_length, out);
}